// Round 7
// baseline (176.131 us; speedup 1.0000x reference)
//
#include <hip/hip_runtime.h>

namespace {
constexpr int kB = 16, kT = 2048, kC = 512, kH = 4, kU = 250, kDH = 128;
constexpr int kPitchT = 2056;   // V row pitch in shorts: 4112 B rows (16B-aligned, breaks 4KB stride)
}

typedef __attribute__((ext_vector_type(8))) short short8;
typedef __attribute__((ext_vector_type(4))) float float4v;

// packed f32x2 -> bf16x2 (RNE), single VALU op; lo = src0, hi = src1
__device__ __forceinline__ unsigned int pk_bf16(float lo, float hi) {
    unsigned int r;
    asm volatile("v_cvt_pk_bf16_f32 %0, %1, %2" : "=v"(r) : "v"(lo), "v"(hi));
    return r;
}
__device__ __forceinline__ float exp2_fast(float x) {   // 2^x, raw v_exp
    float r;
    asm volatile("v_exp_f32 %0, %1" : "=v"(r) : "v"(x));
    return r;
}

// ---------------- K1: alpha branch + V transpose emit ----------------
// block = 4 waves = 32 consecutive t of one b; wave = 8 t rows x full C (lane owns 8 c).
// Interior conv halos via LDS exchange (round-0 proven). Side output: the held
// 8t x 8c register tile, transposed in-register to bf16 V[b][c][t] (one 16-B
// store per c). Read 67 MB + write 34 MB: pure streaming, no cross-block deps.
__global__ __launch_bounds__(256) void k1_alpha(
    const float* __restrict__ hid, const float* __restrict__ mask,
    const float* __restrict__ conv_w, const float* __restrict__ conv_b,
    const float* __restrict__ lin_w, const float* __restrict__ lin_b,
    float* __restrict__ alpha_raw, unsigned short* __restrict__ Vt)
{
    __shared__ float halo[4][2][512];   // 16 KB: [wave][first/last core row][c]
    const int wave = threadIdx.x >> 6, lane = threadIdx.x & 63;
    const int b = blockIdx.x >> 6;             // 64 blocks per b
    const int tblk = (blockIdx.x & 63) << 5;   // 32 t per block
    const int t0 = tblk + wave * 8;
    const int c0 = lane * 8;

    float cw[24], cb[8], lw[8];
    #pragma unroll
    for (int i = 0; i < 6; i++) *(float4*)&cw[i*4] = ((const float4*)(conv_w + c0*3))[i];
    *(float4*)&cb[0] = *(const float4*)(conv_b + c0);
    *(float4*)&cb[4] = *(const float4*)(conv_b + c0 + 4);
    *(float4*)&lw[0] = *(const float4*)(lin_w + c0);
    *(float4*)&lw[4] = *(const float4*)(lin_w + c0 + 4);
    const float lb = lin_b[0];

    float r[10][8];
    const float* base = hid + ((size_t)b * kT + t0) * kC + c0;
    #pragma unroll
    for (int i = 1; i <= 8; i++) {              // core rows t0 .. t0+7
        const float* p = base + (ptrdiff_t)(i - 1) * kC;
        *(float4*)&r[i][0] = *(const float4*)p;
        *(float4*)&r[i][4] = *(const float4*)(p + 4);
    }
    // publish boundary core rows
    *(float4*)&halo[wave][0][c0]     = *(float4*)&r[1][0];
    *(float4*)&halo[wave][0][c0 + 4] = *(float4*)&r[1][4];
    *(float4*)&halo[wave][1][c0]     = *(float4*)&r[8][0];
    *(float4*)&halo[wave][1][c0 + 4] = *(float4*)&r[8][4];

    // block-boundary halos from HBM (or zeros at sequence edges)
    if (wave == 0) {
        if (tblk > 0) {
            const float* p = base - kC;
            *(float4*)&r[0][0] = *(const float4*)p;
            *(float4*)&r[0][4] = *(const float4*)(p + 4);
        } else {
            #pragma unroll
            for (int j = 0; j < 8; j++) r[0][j] = 0.f;
        }
    }
    if (wave == 3) {
        if (tblk + 32 < kT) {
            const float* p = base + 8 * kC;
            *(float4*)&r[9][0] = *(const float4*)p;
            *(float4*)&r[9][4] = *(const float4*)(p + 4);
        } else {
            #pragma unroll
            for (int j = 0; j < 8; j++) r[9][j] = 0.f;
        }
    }

    // V transpose emit (independent of halos): 8 stores of 16 B, one per channel
    #pragma unroll
    for (int e = 0; e < 8; e++) {
        unsigned int vw[4];
        vw[0] = pk_bf16(r[1][e], r[2][e]);
        vw[1] = pk_bf16(r[3][e], r[4][e]);
        vw[2] = pk_bf16(r[5][e], r[6][e]);
        vw[3] = pk_bf16(r[7][e], r[8][e]);
        *(uint4*)(Vt + ((size_t)b * kC + c0 + e) * kPitchT + t0) = *(const uint4*)vw;
    }

    __syncthreads();
    if (wave > 0) {
        *(float4*)&r[0][0] = *(float4*)&halo[wave - 1][1][c0];
        *(float4*)&r[0][4] = *(float4*)&halo[wave - 1][1][c0 + 4];
    }
    if (wave < 3) {
        *(float4*)&r[9][0] = *(float4*)&halo[wave + 1][0][c0];
        *(float4*)&r[9][4] = *(float4*)&halo[wave + 1][0][c0 + 4];
    }

    float sums[8];
    #pragma unroll
    for (int j = 0; j < 8; j++) {
        float acc = 0.f;
        #pragma unroll
        for (int k = 0; k < 8; k++) {
            float m = fmaf(r[j][k], cw[k*3],
                      fmaf(r[j+1][k], cw[k*3+1],
                      fmaf(r[j+2][k], cw[k*3+2], cb[k])));
            float v = m + r[j+1][k];          // memory + context
            v = v > 0.f ? v : 0.f;            // relu
            acc = fmaf(v, lw[k], acc);
        }
        #pragma unroll
        for (int off = 32; off >= 1; off >>= 1) acc += __shfl_xor(acc, off, 64);
        sums[j] = acc;
    }
    if (lane == 0) {
        #pragma unroll
        for (int j = 0; j < 8; j++) {
            float s = sums[j] + lb;
            float a = 1.f / (1.f + expf(-s));  // relu(sigmoid*1-0) == sigmoid
            alpha_raw[(size_t)b * kT + t0 + j] = a * mask[(size_t)b * kT + t0 + j];
        }
    }
}

// ---------------- K2: per-b scan (once, not x32) ----------------
// 16 blocks x 256 thr. alpha_raw -> token_num, scale, masked-scaled cumsum al[b][t]
// (1e30 sentinel where mask==0), out_tok, out_alpha.
__global__ __launch_bounds__(256) void k2_scan(
    const float* __restrict__ alpha_raw, const float* __restrict__ mask,
    const int* __restrict__ target,
    float* __restrict__ al, float* __restrict__ out_tok, float* __restrict__ out_alpha)
{
    __shared__ float woff[4];
    __shared__ float s_tot;
    const int b = blockIdx.x, tid = threadIdx.x;
    const int wave = tid >> 6, lane = tid & 63;

    float a[8], m[8];
    const float* ar = alpha_raw + (size_t)b * kT + tid * 8;
    const float* mr = mask + (size_t)b * kT + tid * 8;
    *(float4*)&a[0] = *(const float4*)ar;
    *(float4*)&a[4] = *(const float4*)(ar + 4);
    *(float4*)&m[0] = *(const float4*)mr;
    *(float4*)&m[4] = *(const float4*)(mr + 4);

    float pre[8]; float run = 0.f;
    #pragma unroll
    for (int j = 0; j < 8; j++) { run += a[j]; pre[j] = run; }
    float sc = run;
    #pragma unroll
    for (int off = 1; off <= 32; off <<= 1) {
        float v = __shfl_up(sc, off, 64);
        sc = (lane >= off) ? sc + v : sc;
    }
    if (lane == 63) woff[wave] = sc;
    __syncthreads();
    if (tid == 0) {
        float r2 = 0.f;
        #pragma unroll
        for (int w = 0; w < 4; w++) { float x = woff[w]; woff[w] = r2; r2 += x; }
        s_tot = r2;
    }
    __syncthreads();
    const float tot = s_tot;
    const float scale = (tot != 0.f) ? ((float)target[b] / tot) : 0.f;
    const float basev = woff[wave] + (sc - run);

    float alv[8], oav[8];
    #pragma unroll
    for (int j = 0; j < 8; j++) {
        alv[j] = (m[j] > 0.f) ? (basev + pre[j]) * scale : 1.0e30f;
        oav[j] = a[j] * scale;
    }
    float* alw = al + (size_t)b * kT + tid * 8;
    float* oaw = out_alpha + (size_t)b * kT + tid * 8;
    *(float4*)alw       = *(const float4*)&alv[0];
    *(float4*)(alw + 4) = *(const float4*)&alv[4];
    *(float4*)oaw       = *(const float4*)&oav[0];
    *(float4*)(oaw + 4) = *(const float4*)&oav[4];
    if (tid == 0) out_tok[b] = tot;
}

// ---------------- K3: banded MFMA attention from global transposed V ----------------
// grid (ug=8, h=4, b=16) = 512 blocks x 256 thr (2 blocks/CU, 8 waves/CU).
// Wave owns 16 u x 64 d: ut = wave&1 (u-tile), dh = wave>>1 (d-half).
// al[b] cached in LDS (8 KB only). Per-lane exact softmax max via binary search
// on monotone al; wave band |du-al| <= sqrt(dmax^2+21/sig^2); per 32-t chunk:
// P in-register (log2-domain exp), 4 B-fragments = 4 x 16-B global loads from
// V[b][c][t] (quad-lanes read 64 B contiguous), 4 MFMA. No staging, no barriers.
__global__ __launch_bounds__(256, 2) void k3_attn(
    const unsigned short* __restrict__ Vt, const float* __restrict__ al,
    const float* __restrict__ sigma, float* __restrict__ out_ac)
{
    __shared__ float al_s[kT];   // 8 KB

    const int ug = blockIdx.x, h = blockIdx.y, b = blockIdx.z;
    const int tid = threadIdx.x;
    const int wave = tid >> 6, lane = tid & 63;
    const int lm = lane & 15, quad = lane >> 4;
    const int ut = wave & 1, dh = wave >> 1;
    const int u0 = ug * 32 + ut * 16;
    const int cb = h * kDH + dh * 64;
    const float sig = sigma[h];
    const float sigL = sig * 1.2011224f;          // sig * sqrt(log2 e)

    {   // stage alignment into LDS (2 x float4 per thread)
        const float4* alg = (const float4*)(al + (size_t)b * kT);
        ((float4*)al_s)[tid]       = alg[tid];
        ((float4*)al_s)[tid + 256] = alg[tid + 256];
    }
    __syncthreads();

    // per-lane u: exact softmax max via binary search (al_s monotone)
    const float du = (float)(u0 + lm) + 0.5f;
    const float duL = du * sigL;
    int pos = 0;
    #pragma unroll
    for (int stp = 1024; stp >= 1; stp >>= 1) {
        int np = pos + stp;
        pos = (al_s[np - 1] < du) ? np : pos;
    }
    float d1 = (pos < kT) ? al_s[pos] - du : 3.0e30f;
    float d0 = (pos > 0) ? du - al_s[pos - 1] : 3.0e30f;
    float dmin = fminf(d0, d1);
    float ms = fminf(dmin, 1.0e4f) * sigL;
    const float mu_pos = ms * ms;                 // = -max_score in log2 units

    // wave band: |du - al| <= sqrt(dmax^2 + 21/sig^2)
    float dmax_l = fminf(dmin, 1.0e4f);
    #pragma unroll
    for (int off = 8; off >= 1; off >>= 1) dmax_l = fmaxf(dmax_l, __shfl_xor(dmax_l, off, 64));
    const float c21 = (sig > 1e-3f) ? 21.0f / (sig * sig) : 9.0e60f;
    const float bound = sqrtf(fmaf(dmax_l, dmax_l, c21));
    const float lo_b = (float)u0 + 0.5f - bound;
    const float hi_b = (float)u0 + 15.5f + bound;
    int p_lo = 0, p_hi = 0;
    #pragma unroll
    for (int stp = 1024; stp >= 1; stp >>= 1) {
        int n1 = p_lo + stp; p_lo = (al_s[n1 - 1] < lo_b) ? n1 : p_lo;
        int n2 = p_hi + stp; p_hi = (al_s[n2 - 1] < hi_b) ? n2 : p_hi;
    }
    const int ks_lo = p_lo >> 5;
    const int ks_end = (p_hi + 31) >> 5;

    float4v acc0 = (float4v)(0.f), acc1 = (float4v)(0.f);
    float4v acc2 = (float4v)(0.f), acc3 = (float4v)(0.f);
    float lsum = 0.f;

    const unsigned short* vrow = Vt + ((size_t)b * kC + cb + lm) * kPitchT + quad * 8;

    #pragma unroll 2
    for (int kg = ks_lo; kg < ks_end; kg++) {
        const int kb = kg * 32;
        float alv[8];
        *(float4*)&alv[0] = *(const float4*)&al_s[kb + quad * 8];
        *(float4*)&alv[4] = *(const float4*)&al_s[kb + quad * 8 + 4];

        float ev[8];
        #pragma unroll
        for (int j = 0; j < 8; j++) {
            float d = fmaf(-alv[j], sigL, duL);       // (du - al) * sigL
            float e = exp2_fast(fmaf(-d, d, mu_pos)); // 2^(mu' - d'^2) <= 1
            lsum += e;
            ev[j] = e;
        }
        union { short8 s; unsigned int w[4]; } af;
        af.w[0] = pk_bf16(ev[0], ev[1]);
        af.w[1] = pk_bf16(ev[2], ev[3]);
        af.w[2] = pk_bf16(ev[4], ev[5]);
        af.w[3] = pk_bf16(ev[6], ev[7]);

        const unsigned short* vp = vrow + kb;
        short8 bf0 = *(const short8*)(vp);
        short8 bf1 = *(const short8*)(vp + 16 * kPitchT);
        short8 bf2 = *(const short8*)(vp + 32 * kPitchT);
        short8 bf3 = *(const short8*)(vp + 48 * kPitchT);
        acc0 = __builtin_amdgcn_mfma_f32_16x16x32_bf16(af.s, bf0, acc0, 0, 0, 0);
        acc1 = __builtin_amdgcn_mfma_f32_16x16x32_bf16(af.s, bf1, acc1, 0, 0, 0);
        acc2 = __builtin_amdgcn_mfma_f32_16x16x32_bf16(af.s, bf2, acc2, 0, 0, 0);
        acc3 = __builtin_amdgcn_mfma_f32_16x16x32_bf16(af.s, bf3, acc3, 0, 0, 0);
    }

    // epilogue: full P-row sums (over quads), normalize, direct store (disjoint)
    float lv = lsum;
    lv += __shfl_xor(lv, 16, 64);
    lv += __shfl_xor(lv, 32, 64);        // every lane: full l for u = u0 + lm
    #pragma unroll
    for (int r = 0; r < 4; r++) {
        const int ur = quad * 4 + r;
        float rl = __shfl(lv, ur, 64);   // l for u = u0 + ur
        float linv = (rl > 1e-30f) ? 1.f / rl : 0.f;
        const int u = u0 + ur;
        if (u < kU) {
            float* dst = out_ac + ((size_t)(b * kU + u)) * kC + cb + lm;
            dst[0]  = acc0[r] * linv;
            dst[16] = acc1[r] * linv;
            dst[32] = acc2[r] * linv;
            dst[48] = acc3[r] * linv;
        }
    }
}

extern "C" void kernel_launch(void* const* d_in, const int* in_sizes, int n_in,
                              void* d_out, int out_size, void* d_ws, size_t ws_size,
                              hipStream_t stream) {
    const float* hid    = (const float*)d_in[0];
    const float* mask   = (const float*)d_in[1];
    const int*   tgt    = (const int*)d_in[2];
    // d_in[3] = max_token scalar (compile-time kU=250)
    const float* conv_w = (const float*)d_in[4];
    const float* conv_b = (const float*)d_in[5];
    const float* lin_w  = (const float*)d_in[6];
    const float* lin_b  = (const float*)d_in[7];
    const float* sigma  = (const float*)d_in[8];
    // d_in[9] = sigma_bias: constant over t -> cancels in softmax; unused.

    float* alpha_raw = (float*)d_ws;                                   // [B*T] f32
    float* al        = (float*)((char*)d_ws + 131072);                 // [B*T] f32
    unsigned short* Vt = (unsigned short*)((char*)d_ws + 262144);      // [B][C][pitchT] bf16, 33.7 MB

    float* out_ac    = (float*)d_out;                    // [B, U, C]
    float* out_tok   = out_ac + (size_t)kB * kU * kC;    // [B]
    float* out_alpha = out_tok + kB;                     // [B, T]

    k1_alpha<<<kB * kT / 32, 256, 0, stream>>>(hid, mask, conv_w, conv_b, lin_w, lin_b,
                                               alpha_raw, Vt);
    k2_scan<<<kB, 256, 0, stream>>>(alpha_raw, mask, tgt, al, out_tok, out_alpha);
    k3_attn<<<dim3(8, kH, kB), 256, 0, stream>>>(Vt, al, sigma, out_ac);
}

// Round 8
// 157.601 us; speedup vs baseline: 1.1176x; 1.1176x over previous
//
#include <hip/hip_runtime.h>

namespace {
constexpr int kB = 16, kT = 2048, kC = 512, kH = 4, kU = 250, kDH = 128;
constexpr int kTW = 32;          // V tile width in t
constexpr int kNTB = kT / kTW;   // 64 tiles per b
}

typedef __attribute__((ext_vector_type(8))) short short8;
typedef __attribute__((ext_vector_type(4))) float float4v;

// packed f32x2 -> bf16x2 (RNE), single VALU op; lo = src0, hi = src1
__device__ __forceinline__ unsigned int pk_bf16(float lo, float hi) {
    unsigned int r;
    asm volatile("v_cvt_pk_bf16_f32 %0, %1, %2" : "=v"(r) : "v"(lo), "v"(hi));
    return r;
}
__device__ __forceinline__ float exp2_fast(float x) {   // 2^x, raw v_exp
    float r;
    asm volatile("v_exp_f32 %0, %1" : "=v"(r) : "v"(x));
    return r;
}

// ---------------- K1: alpha branch + tiled V transpose emit ----------------
// block = 4 waves = 32 consecutive t of one b (= exactly one V tile tb).
// V layout: Vt[b][tb][c][32t] bf16 -- every 32-KB tile written entirely by ONE
// block (L2 lines fully dirtied locally; round-7's [c][t] pitch layout split
// each 128-B line across two blocks on different XCDs -> HBM RMW, ~2x write amp).
__global__ __launch_bounds__(256) void k1_alpha(
    const float* __restrict__ hid, const float* __restrict__ mask,
    const float* __restrict__ conv_w, const float* __restrict__ conv_b,
    const float* __restrict__ lin_w, const float* __restrict__ lin_b,
    float* __restrict__ alpha_raw, unsigned short* __restrict__ Vt)
{
    __shared__ float halo[4][2][512];   // 16 KB: [wave][first/last core row][c]
    const int wave = threadIdx.x >> 6, lane = threadIdx.x & 63;
    const int b = blockIdx.x >> 6;             // 64 blocks per b
    const int tb = blockIdx.x & 63;            // tile index = t-block
    const int tblk = tb << 5;                  // 32 t per block
    const int t0 = tblk + wave * 8;
    const int c0 = lane * 8;

    float cw[24], cb[8], lw[8];
    #pragma unroll
    for (int i = 0; i < 6; i++) *(float4*)&cw[i*4] = ((const float4*)(conv_w + c0*3))[i];
    *(float4*)&cb[0] = *(const float4*)(conv_b + c0);
    *(float4*)&cb[4] = *(const float4*)(conv_b + c0 + 4);
    *(float4*)&lw[0] = *(const float4*)(lin_w + c0);
    *(float4*)&lw[4] = *(const float4*)(lin_w + c0 + 4);
    const float lb = lin_b[0];

    float r[10][8];
    const float* base = hid + ((size_t)b * kT + t0) * kC + c0;
    #pragma unroll
    for (int i = 1; i <= 8; i++) {              // core rows t0 .. t0+7
        const float* p = base + (ptrdiff_t)(i - 1) * kC;
        *(float4*)&r[i][0] = *(const float4*)p;
        *(float4*)&r[i][4] = *(const float4*)(p + 4);
    }
    // publish boundary core rows
    *(float4*)&halo[wave][0][c0]     = *(float4*)&r[1][0];
    *(float4*)&halo[wave][0][c0 + 4] = *(float4*)&r[1][4];
    *(float4*)&halo[wave][1][c0]     = *(float4*)&r[8][0];
    *(float4*)&halo[wave][1][c0 + 4] = *(float4*)&r[8][4];

    // block-boundary halos from HBM (or zeros at sequence edges)
    if (wave == 0) {
        if (tblk > 0) {
            const float* p = base - kC;
            *(float4*)&r[0][0] = *(const float4*)p;
            *(float4*)&r[0][4] = *(const float4*)(p + 4);
        } else {
            #pragma unroll
            for (int j = 0; j < 8; j++) r[0][j] = 0.f;
        }
    }
    if (wave == 3) {
        if (tblk + 32 < kT) {
            const float* p = base + 8 * kC;
            *(float4*)&r[9][0] = *(const float4*)p;
            *(float4*)&r[9][4] = *(const float4*)(p + 4);
        } else {
            #pragma unroll
            for (int j = 0; j < 8; j++) r[9][j] = 0.f;
        }
    }

    // tiled V emit: lane stores 16 B per owned channel at [c][wave*8 t]
    {
        unsigned short* tile = Vt + (size_t)(b * kNTB + tb) * kC * kTW;
        #pragma unroll
        for (int e = 0; e < 8; e++) {
            unsigned int vw[4];
            vw[0] = pk_bf16(r[1][e], r[2][e]);
            vw[1] = pk_bf16(r[3][e], r[4][e]);
            vw[2] = pk_bf16(r[5][e], r[6][e]);
            vw[3] = pk_bf16(r[7][e], r[8][e]);
            *(uint4*)(tile + (c0 + e) * kTW + wave * 8) = *(const uint4*)vw;
        }
    }

    __syncthreads();
    if (wave > 0) {
        *(float4*)&r[0][0] = *(float4*)&halo[wave - 1][1][c0];
        *(float4*)&r[0][4] = *(float4*)&halo[wave - 1][1][c0 + 4];
    }
    if (wave < 3) {
        *(float4*)&r[9][0] = *(float4*)&halo[wave + 1][0][c0];
        *(float4*)&r[9][4] = *(float4*)&halo[wave + 1][0][c0 + 4];
    }

    float sums[8];
    #pragma unroll
    for (int j = 0; j < 8; j++) {
        float acc = 0.f;
        #pragma unroll
        for (int k = 0; k < 8; k++) {
            float m = fmaf(r[j][k], cw[k*3],
                      fmaf(r[j+1][k], cw[k*3+1],
                      fmaf(r[j+2][k], cw[k*3+2], cb[k])));
            float v = m + r[j+1][k];          // memory + context
            v = v > 0.f ? v : 0.f;            // relu
            acc = fmaf(v, lw[k], acc);
        }
        #pragma unroll
        for (int off = 32; off >= 1; off >>= 1) acc += __shfl_xor(acc, off, 64);
        sums[j] = acc;
    }
    if (lane == 0) {
        #pragma unroll
        for (int j = 0; j < 8; j++) {
            float s = sums[j] + lb;
            float a = 1.f / (1.f + expf(-s));  // relu(sigmoid*1-0) == sigmoid
            alpha_raw[(size_t)b * kT + t0 + j] = a * mask[(size_t)b * kT + t0 + j];
        }
    }
}

// ---------------- K2: per-b scan (once) ----------------
__global__ __launch_bounds__(256) void k2_scan(
    const float* __restrict__ alpha_raw, const float* __restrict__ mask,
    const int* __restrict__ target,
    float* __restrict__ al, float* __restrict__ out_tok, float* __restrict__ out_alpha)
{
    __shared__ float woff[4];
    __shared__ float s_tot;
    const int b = blockIdx.x, tid = threadIdx.x;
    const int wave = tid >> 6, lane = tid & 63;

    float a[8], m[8];
    const float* ar = alpha_raw + (size_t)b * kT + tid * 8;
    const float* mr = mask + (size_t)b * kT + tid * 8;
    *(float4*)&a[0] = *(const float4*)ar;
    *(float4*)&a[4] = *(const float4*)(ar + 4);
    *(float4*)&m[0] = *(const float4*)mr;
    *(float4*)&m[4] = *(const float4*)(mr + 4);

    float pre[8]; float run = 0.f;
    #pragma unroll
    for (int j = 0; j < 8; j++) { run += a[j]; pre[j] = run; }
    float sc = run;
    #pragma unroll
    for (int off = 1; off <= 32; off <<= 1) {
        float v = __shfl_up(sc, off, 64);
        sc = (lane >= off) ? sc + v : sc;
    }
    if (lane == 63) woff[wave] = sc;
    __syncthreads();
    if (tid == 0) {
        float r2 = 0.f;
        #pragma unroll
        for (int w = 0; w < 4; w++) { float x = woff[w]; woff[w] = r2; r2 += x; }
        s_tot = r2;
    }
    __syncthreads();
    const float tot = s_tot;
    const float scale = (tot != 0.f) ? ((float)target[b] / tot) : 0.f;
    const float basev = woff[wave] + (sc - run);

    float alv[8], oav[8];
    #pragma unroll
    for (int j = 0; j < 8; j++) {
        alv[j] = (m[j] > 0.f) ? (basev + pre[j]) * scale : 1.0e30f;
        oav[j] = a[j] * scale;
    }
    float* alw = al + (size_t)b * kT + tid * 8;
    float* oaw = out_alpha + (size_t)b * kT + tid * 8;
    *(float4*)alw       = *(const float4*)&alv[0];
    *(float4*)(alw + 4) = *(const float4*)&alv[4];
    *(float4*)oaw       = *(const float4*)&oav[0];
    *(float4*)(oaw + 4) = *(const float4*)&oav[4];
    if (tid == 0) out_tok[b] = tot;
}

// ---------------- K3: banded MFMA attention, tiled V, tight per-lane bands ----------------
// grid (ut=16, h=4, b=16) = 1024 blocks x 256 thr, launch_bounds(256,4) -> up to
// 16 waves/CU. Wave owns 16 u x 32 c (dq = wave). Band bound is PER-LANE:
// lo_l = du - sqrt(dmin_l^2 + 21/sig^2), wave band = [min lo_l, max hi_l] -- the
// round-7 shared bound (u0+0.5 - sqrt(dmax^2+c21)) degenerated to full-T for every
// beyond-target u-tile (the 46-us tail). Fragment loads: 16 c-rows x 64 B = 1 KB
// CONTIGUOUS per instruction from the tiled layout.
__global__ __launch_bounds__(256, 4) void k3_attn(
    const unsigned short* __restrict__ Vt, const float* __restrict__ al,
    const float* __restrict__ sigma, float* __restrict__ out_ac)
{
    __shared__ float al_s[kT];   // 8 KB

    const int ut = blockIdx.x, h = blockIdx.y, b = blockIdx.z;
    const int tid = threadIdx.x;
    const int wave = tid >> 6, lane = tid & 63;
    const int lm = lane & 15, quad = lane >> 4;
    const int u0 = ut * 16;
    const int cb = h * kDH + wave * 32;
    const float sig = sigma[h];
    const float sigL = sig * 1.2011224f;          // sig * sqrt(log2 e)

    {   // stage alignment into LDS (2 x float4 per thread)
        const float4* alg = (const float4*)(al + (size_t)b * kT);
        ((float4*)al_s)[tid]       = alg[tid];
        ((float4*)al_s)[tid + 256] = alg[tid + 256];
    }
    __syncthreads();

    // per-lane u: exact softmax max via binary search (al_s monotone)
    const float du = (float)(u0 + lm) + 0.5f;
    const float duL = du * sigL;
    int pos = 0;
    #pragma unroll
    for (int stp = 1024; stp >= 1; stp >>= 1) {
        int np = pos + stp;
        pos = (al_s[np - 1] < du) ? np : pos;
    }
    float d1 = (pos < kT) ? al_s[pos] - du : 3.0e30f;
    float d0 = (pos > 0) ? du - al_s[pos - 1] : 3.0e30f;
    float dmin = fminf(d0, d1);
    float dmn = fminf(dmin, 1.0e4f);
    float ms = dmn * sigL;
    const float mu_pos = ms * ms;                 // = -max_score in log2 units

    // per-lane tight band: |du - al| <= sqrt(dmin_l^2 + 21/sig^2); wave = union
    const float c21 = (sig > 1e-3f) ? 21.0f / (sig * sig) : 9.0e60f;
    const float bnd = sqrtf(fmaf(dmn, dmn, c21));
    float lo_l = du - bnd, hi_l = du + bnd;
    #pragma unroll
    for (int off = 8; off >= 1; off >>= 1) {
        lo_l = fminf(lo_l, __shfl_xor(lo_l, off, 64));
        hi_l = fmaxf(hi_l, __shfl_xor(hi_l, off, 64));
    }
    int p_lo = 0, p_hi = 0;
    #pragma unroll
    for (int stp = 1024; stp >= 1; stp >>= 1) {
        int n1 = p_lo + stp; p_lo = (al_s[n1 - 1] < lo_l) ? n1 : p_lo;
        int n2 = p_hi + stp; p_hi = (al_s[n2 - 1] < hi_l) ? n2 : p_hi;
    }
    const int ks_lo = p_lo >> 5;
    const int ks_end = (p_hi + 31) >> 5;

    float4v acc0 = (float4v)(0.f), acc1 = (float4v)(0.f);
    float lsum = 0.f;

    // tiled V: frag base = rows (cb+lm), quad picks k-slice (t within tile)
    const unsigned short* vbase = Vt + (size_t)b * kNTB * kC * kTW
                                     + (cb + lm) * kTW + quad * 8;

    #pragma unroll 4
    for (int kg = ks_lo; kg < ks_end; kg++) {
        const int kb = kg * kTW;
        float alv[8];
        *(float4*)&alv[0] = *(const float4*)&al_s[kb + quad * 8];
        *(float4*)&alv[4] = *(const float4*)&al_s[kb + quad * 8 + 4];

        float ev[8];
        #pragma unroll
        for (int j = 0; j < 8; j++) {
            float d = fmaf(-alv[j], sigL, duL);       // (du - al) * sigL
            float e = exp2_fast(fmaf(-d, d, mu_pos)); // 2^(mu' - d'^2) <= 1
            lsum += e;
            ev[j] = e;
        }
        union { short8 s; unsigned int w[4]; } af;
        af.w[0] = pk_bf16(ev[0], ev[1]);
        af.w[1] = pk_bf16(ev[2], ev[3]);
        af.w[2] = pk_bf16(ev[4], ev[5]);
        af.w[3] = pk_bf16(ev[6], ev[7]);

        const unsigned short* vp = vbase + (size_t)kg * kC * kTW;
        short8 bf0 = *(const short8*)(vp);
        short8 bf1 = *(const short8*)(vp + 16 * kTW);
        acc0 = __builtin_amdgcn_mfma_f32_16x16x32_bf16(af.s, bf0, acc0, 0, 0, 0);
        acc1 = __builtin_amdgcn_mfma_f32_16x16x32_bf16(af.s, bf1, acc1, 0, 0, 0);
    }

    // epilogue: full P-row sums (over quads), normalize, direct store (disjoint)
    float lv = lsum;
    lv += __shfl_xor(lv, 16, 64);
    lv += __shfl_xor(lv, 32, 64);        // every lane: full l for u = u0 + lm
    #pragma unroll
    for (int r = 0; r < 4; r++) {
        const int ur = quad * 4 + r;
        float rl = __shfl(lv, ur, 64);   // l for u = u0 + ur
        float linv = (rl > 1e-30f) ? 1.f / rl : 0.f;
        const int u = u0 + ur;
        if (u < kU) {
            float* dst = out_ac + ((size_t)(b * kU + u)) * kC + cb + lm;
            dst[0]  = acc0[r] * linv;
            dst[16] = acc1[r] * linv;
        }
    }
}

extern "C" void kernel_launch(void* const* d_in, const int* in_sizes, int n_in,
                              void* d_out, int out_size, void* d_ws, size_t ws_size,
                              hipStream_t stream) {
    const float* hid    = (const float*)d_in[0];
    const float* mask   = (const float*)d_in[1];
    const int*   tgt    = (const int*)d_in[2];
    // d_in[3] = max_token scalar (compile-time kU=250)
    const float* conv_w = (const float*)d_in[4];
    const float* conv_b = (const float*)d_in[5];
    const float* lin_w  = (const float*)d_in[6];
    const float* lin_b  = (const float*)d_in[7];
    const float* sigma  = (const float*)d_in[8];
    // d_in[9] = sigma_bias: constant over t -> cancels in softmax; unused.

    float* alpha_raw = (float*)d_ws;                                   // [B*T] f32
    float* al        = (float*)((char*)d_ws + 131072);                 // [B*T] f32
    unsigned short* Vt = (unsigned short*)((char*)d_ws + 262144);      // [B][64][C][32] bf16, 32 MB

    float* out_ac    = (float*)d_out;                    // [B, U, C]
    float* out_tok   = out_ac + (size_t)kB * kU * kC;    // [B]
    float* out_alpha = out_tok + kB;                     // [B, T]

    k1_alpha<<<kB * kT / 32, 256, 0, stream>>>(hid, mask, conv_w, conv_b, lin_w, lin_b,
                                               alpha_raw, Vt);
    k2_scan<<<kB, 256, 0, stream>>>(alpha_raw, mask, tgt, al, out_tok, out_alpha);
    k3_attn<<<dim3(16, kH, kB), 256, 0, stream>>>(Vt, al, sigma, out_ac);
}